// Round 35
// baseline (19.226 us; speedup 1.0000x reference)
//
#include <hip/hip_runtime.h>

// ---------------------------------------------------------------------------
// FFT_Conv_Layer == 3x3 "same" spatial conv with flipped REAL filter plane:
//   out[b,o,y,x] = sum_{i,ky,kx} filts[0,i,o,ky,kx,0] * img[b,i,y+1-ky,x+1-kx]
//
// Ladder: R25/R34 champion 18.53/18.35us. R32 counters, re-normalized:
// SQ_LDS_BANK_CONFLICT = 2.36M/stage = ~9.2K cyc/CU = 3.8us of the 9.5us
// stage phase — the wf scatter's same-bank writes (same-tap lanes Δo=1 ->
// Δ1024B -> bank 0, ~8-way). R35: SKEWED wf LDS layout,
//   byte(c) = c*16 + (c>>6)*16 + (c>>9)*32
// -> Δo=1: Δbank 4; Δt=1: Δbank 8 (writes spread), while K-loop B-reads
// stay lane-linear (conflict-free): within group g=(t*2+kc)*4+n the address
// is wfl + t*8352 + (kc*4+n)*1040 + l*16. Everything else R25-verbatim.
// ---------------------------------------------------------------------------

typedef _Float16 f16x8 __attribute__((ext_vector_type(8)));
typedef float    f32x4 __attribute__((ext_vector_type(4)));

#define NB 16
#define NC 64
#define NH 64
#define NW 64
#define CHUNKS 528                 // 66 xp positions * 8 channel-chunks per slab
#define SLAB_BYTES (CHUNKS * 16)   // 8448 B per image row slab
#define IMG_LDS (6 * SLAB_BYTES)   // 50,688 B
#define WF_LDS 75136               // skewed wf buffer (4608 chunks + pads)

__global__ __launch_bounds__(512, 1) void conv_one(const float* __restrict__ imgs,
                                                   const float* __restrict__ filts,
                                                   float* __restrict__ out) {
    __shared__ char lds[IMG_LDS + WF_LDS];   // 125,824 B
    char* wfl = lds + IMG_LDS;
    const int bid = blockIdx.x;
    const int swz = ((bid & 7) << 5) | (bid >> 3);   // bijective: 256 = 8*32
    const int b   = swz >> 4;
    const int y0  = (swz & 15) << 2;     // first of 4 output rows
    const int tid = threadIdx.x;
    const int w   = tid >> 6;            // wave 0..7
    const int l   = tid & 63;
    const int h   = l >> 4;              // k-chunk lane group
    const int r   = l & 15;              // A-row / B-col within fragment

    // ---- pads: 6 slabs x 16 chunks (xp = 0, 65) ----
    if (tid < 96) {
        const int sl  = tid >> 4;
        const int rem = tid & 15;
        const int ci  = rem >> 1;
        const int xp2 = (rem & 1) ? 65 : 0;
        const int c2  = xp2 * 8 + (ci ^ (xp2 & 7));
        f16x8 z;
        #pragma unroll
        for (int k = 0; k < 8; ++k) z[k] = (_Float16)0.f;
        *reinterpret_cast<f16x8*>(lds + sl * SLAB_BYTES + c2 * 16) = z;
    }

    // ---- image: stage 6 slabs (rows y0-1 .. y0+4), 48 jobs over 8 waves ----
    #pragma unroll
    for (int j = 0; j < 6; ++j) {
        const int job = w + j * 8;
        const int sl  = job >> 3;
        const int ci  = job & 7;
        const int yy  = y0 - 1 + sl;
        float fr[8];
        if ((unsigned)yy < (unsigned)NH) {
            const float* src = imgs + (((size_t)(b * NC + ci * 8)) * NH + yy) * NW + l;
            #pragma unroll
            for (int k = 0; k < 8; ++k) fr[k] = src[(size_t)k * NH * NW];
        } else {
            #pragma unroll
            for (int k = 0; k < 8; ++k) fr[k] = 0.f;
        }
        f16x8 v;
        #pragma unroll
        for (int k = 0; k < 8; ++k) v[k] = (_Float16)fr[k];
        const int xp = l + 1;
        const int chunk = xp * 8 + (ci ^ (xp & 7));
        *reinterpret_cast<f16x8*>(lds + sl * SLAB_BYTES + chunk * 16) = v;
    }

    // ---- wf: coalesced gather + SKEWED LDS scatter (72 entries/thread) ----
    {
        const float2* filts2 = reinterpret_cast<const float2*>(filts);
        #pragma unroll
        for (int k = 0; k < 72; ++k) {
            const int f = tid + k * 512;         // entry = i*576 + o*9 + t
            const float v = filts2[f].x;         // real plane
            const int i   = f / 576;
            const int rem = f - i * 576;
            const int o   = rem / 9;
            const int t   = rem - o * 9;
            const int kc = i >> 5, hh = (i >> 3) & 3, e = i & 7;
            const int n  = o >> 4,  rr = o & 15;
            const int c  = ((t * 2 + kc) * 4 + n) * 64 + hh * 16 + rr;
            const int byteoff = (c << 4) + ((c >> 6) << 4) + ((c >> 9) << 5);
            *reinterpret_cast<_Float16*>(wfl + byteoff + e * 2) = (_Float16)v;
        }
    }
    __syncthreads();

    const int row = w >> 1;              // output row within quad (0..3)
    const int xh  = w & 1;               // x half (0..1)

    f32x4 acc[2][4];
    #pragma unroll
    for (int m = 0; m < 2; ++m)
        #pragma unroll
        for (int n = 0; n < 4; ++n)
            acc[m][n] = f32x4{0.f, 0.f, 0.f, 0.f};

    #pragma unroll
    for (int ky = 0; ky < 3; ++ky) {
        const char* slab = lds + (row + 2 - ky) * SLAB_BYTES;   // sl in 0..5
        #pragma unroll
        for (int kx = 0; kx < 3; ++kx) {
            const int t = ky * 3 + kx;
            const char* wt = wfl + (size_t)t * 8352;   // skewed tap stride
            #pragma unroll
            for (int kc = 0; kc < 2; ++kc) {
                f16x8 a[2], bb[4];
                #pragma unroll
                for (int m = 0; m < 2; ++m) {
                    const int xp = xh * 32 + m * 16 + r + 2 - kx;  // 0..65
                    const int chunk = xp * 8 + (((kc << 2) + h) ^ (xp & 7));
                    a[m] = *reinterpret_cast<const f16x8*>(slab + chunk * 16);
                }
                #pragma unroll
                for (int n = 0; n < 4; ++n)
                    bb[n] = *reinterpret_cast<const f16x8*>(
                        wt + (size_t)(kc * 4 + n) * 1040 + l * 16);
                #pragma unroll
                for (int m = 0; m < 2; ++m)
                    #pragma unroll
                    for (int n = 0; n < 4; ++n)
                        acc[m][n] = __builtin_amdgcn_mfma_f32_16x16x32_f16(a[m], bb[n], acc[m][n], 0, 0, 0);
            }
        }
    }

    const int y = y0 + row;
    #pragma unroll
    for (int m = 0; m < 2; ++m) {
        const int x0 = xh * 32 + m * 16 + h * 4;
        #pragma unroll
        for (int n = 0; n < 4; ++n) {
            const int o = n * 16 + r;
            *reinterpret_cast<f32x4*>(out + (((size_t)(b * 64 + o) * 64 + y) * 64) + x0) = acc[m][n];
        }
    }
}

extern "C" void kernel_launch(void* const* d_in, const int* in_sizes, int n_in,
                              void* d_out, int out_size, void* d_ws, size_t ws_size,
                              hipStream_t stream) {
    const float* imgs  = (const float*)d_in[0];   // [16][64][64][64] f32
    const float* filts = (const float*)d_in[1];   // [1][64][64][3][3][2] f32
    float* out = (float*)d_out;                   // [16][64][64][64] f32
    (void)d_ws; (void)ws_size;                    // no workspace needed

    hipLaunchKernelGGL(conv_one, dim3(256), dim3(512), 0, stream, imgs, filts, out);
}

// Round 36
// 18.293 us; speedup vs baseline: 1.0510x; 1.0510x over previous
//
#include <hip/hip_runtime.h>

// ---------------------------------------------------------------------------
// FFT_Conv_Layer == 3x3 "same" spatial conv with flipped REAL filter plane:
//   out[b,o,y,x] = sum_{i,ky,kx} filts[0,i,o,ky,kx,0] * img[b,i,y+1-ky,x+1-kx]
// (imag filter plane only reaches the imaginary output, dropped by .real;
//  circular conv at S=66 == full linear conv; crop [1:-1] => "same" conv.)
//
// FINAL = R25 champion (18.35-18.53us across runs; baseline 22.5):
//   - single dispatch, no workspace, no extra launches (R24: launch ovh ~0)
//   - 256 blocks (bijective XCD swizzle) = (b, 4-row quad), 8 waves (512 thr)
//   - LDS 124,416B: image 6 slabs (XOR-swizzled chunks -> conflict-free
//     ds_write_b128/ds_read_b128) + full weight-fragment buffer
//   - wf gather: coalesced float2 reads of L2-resident filts + decode +
//     scatter, overlapped with image staging (R24's uncoalesced version was
//     +29us; R28's DMA version +1us; R35's skewed version +0.9us)
//   - wave tile 32x x 64o: 2m x 4n mfma_f32_16x16x32_f16, A+B from LDS
//   - C/D layout (m89/m91): o = n*16+(lane&15), x = m*16+(lane>>4)*4+j
// Cost decomposition (R27/R32 REPS diagnostics): stage 9.5us (latency-
// structural; issue-order/conflict/TLP levers all neutral) + fixed 5.6us +
// K/store 3.5us. 10 levers measured across 35 rounds; 3 live in this kernel.
// ---------------------------------------------------------------------------

typedef _Float16 f16x8 __attribute__((ext_vector_type(8)));
typedef float    f32x4 __attribute__((ext_vector_type(4)));

#define NB 16
#define NC 64
#define NH 64
#define NW 64
#define CHUNKS 528                 // 66 xp positions * 8 channel-chunks per slab
#define SLAB_BYTES (CHUNKS * 16)   // 8448 B per image row slab
#define IMG_LDS (6 * SLAB_BYTES)   // 50,688 B
#define WF_HALFS (9 * 2 * 4 * 64 * 8)  // 36,864 halfs = 73,728 B = 4608 chunks

__global__ __launch_bounds__(512, 1) void conv_one(const float* __restrict__ imgs,
                                                   const float* __restrict__ filts,
                                                   float* __restrict__ out) {
    __shared__ char lds[IMG_LDS + WF_HALFS * 2];   // 124,416 B
    char* wfl = lds + IMG_LDS;
    const int bid = blockIdx.x;
    const int swz = ((bid & 7) << 5) | (bid >> 3);   // bijective: 256 = 8*32
    const int b   = swz >> 4;
    const int y0  = (swz & 15) << 2;     // first of 4 output rows
    const int tid = threadIdx.x;
    const int w   = tid >> 6;            // wave 0..7
    const int l   = tid & 63;
    const int h   = l >> 4;              // k-chunk lane group
    const int r   = l & 15;              // A-row / B-col within fragment

    // ---- pads: 6 slabs x 16 chunks (xp = 0, 65) ----
    if (tid < 96) {
        const int sl  = tid >> 4;
        const int rem = tid & 15;
        const int ci  = rem >> 1;
        const int xp2 = (rem & 1) ? 65 : 0;
        const int c2  = xp2 * 8 + (ci ^ (xp2 & 7));
        f16x8 z;
        #pragma unroll
        for (int k = 0; k < 8; ++k) z[k] = (_Float16)0.f;
        *reinterpret_cast<f16x8*>(lds + sl * SLAB_BYTES + c2 * 16) = z;
    }

    // ---- image: stage 6 slabs (rows y0-1 .. y0+4), 48 jobs over 8 waves ----
    #pragma unroll
    for (int j = 0; j < 6; ++j) {
        const int job = w + j * 8;
        const int sl  = job >> 3;
        const int ci  = job & 7;
        const int yy  = y0 - 1 + sl;
        float fr[8];
        if ((unsigned)yy < (unsigned)NH) {
            const float* src = imgs + (((size_t)(b * NC + ci * 8)) * NH + yy) * NW + l;
            #pragma unroll
            for (int k = 0; k < 8; ++k) fr[k] = src[(size_t)k * NH * NW];
        } else {
            #pragma unroll
            for (int k = 0; k < 8; ++k) fr[k] = 0.f;
        }
        f16x8 v;
        #pragma unroll
        for (int k = 0; k < 8; ++k) v[k] = (_Float16)fr[k];
        const int xp = l + 1;
        const int chunk = xp * 8 + (ci ^ (xp & 7));
        *reinterpret_cast<f16x8*>(lds + sl * SLAB_BYTES + chunk * 16) = v;
    }

    // ---- wf: coalesced gather + LDS scatter (72 entries/thread) ----
    {
        const float2* filts2 = reinterpret_cast<const float2*>(filts);
        _Float16* wfh = reinterpret_cast<_Float16*>(wfl);
        #pragma unroll
        for (int k = 0; k < 72; ++k) {
            const int f = tid + k * 512;         // entry = i*576 + o*9 + t
            const float v = filts2[f].x;         // real plane
            const int i   = f / 576;
            const int rem = f - i * 576;
            const int o   = rem / 9;
            const int t   = rem - o * 9;
            const int kc = i >> 5, hh = (i >> 3) & 3, e = i & 7;
            const int n  = o >> 4,  rr = o & 15;
            const int c  = ((t * 2 + kc) * 4 + n) * 64 + hh * 16 + rr;
            wfh[c * 8 + e] = (_Float16)v;
        }
    }
    __syncthreads();

    const int row = w >> 1;              // output row within quad (0..3)
    const int xh  = w & 1;               // x half (0..1)

    f32x4 acc[2][4];
    #pragma unroll
    for (int m = 0; m < 2; ++m)
        #pragma unroll
        for (int n = 0; n < 4; ++n)
            acc[m][n] = f32x4{0.f, 0.f, 0.f, 0.f};

    #pragma unroll
    for (int ky = 0; ky < 3; ++ky) {
        const char* slab = lds + (row + 2 - ky) * SLAB_BYTES;   // sl in 0..5
        #pragma unroll
        for (int kx = 0; kx < 3; ++kx) {
            const int t = ky * 3 + kx;
            const char* wt = wfl + (size_t)t * 8192;   // 512 chunks * 16B per tap
            #pragma unroll
            for (int kc = 0; kc < 2; ++kc) {
                f16x8 a[2], bb[4];
                #pragma unroll
                for (int m = 0; m < 2; ++m) {
                    const int xp = xh * 32 + m * 16 + r + 2 - kx;  // 0..65
                    const int chunk = xp * 8 + (((kc << 2) + h) ^ (xp & 7));
                    a[m] = *reinterpret_cast<const f16x8*>(slab + chunk * 16);
                }
                #pragma unroll
                for (int n = 0; n < 4; ++n)
                    bb[n] = *reinterpret_cast<const f16x8*>(
                        wt + (size_t)(kc * 4 + n) * 1024 + l * 16);
                #pragma unroll
                for (int m = 0; m < 2; ++m)
                    #pragma unroll
                    for (int n = 0; n < 4; ++n)
                        acc[m][n] = __builtin_amdgcn_mfma_f32_16x16x32_f16(a[m], bb[n], acc[m][n], 0, 0, 0);
            }
        }
    }

    const int y = y0 + row;
    #pragma unroll
    for (int m = 0; m < 2; ++m) {
        const int x0 = xh * 32 + m * 16 + h * 4;
        #pragma unroll
        for (int n = 0; n < 4; ++n) {
            const int o = n * 16 + r;
            *reinterpret_cast<f32x4*>(out + (((size_t)(b * 64 + o) * 64 + y) * 64) + x0) = acc[m][n];
        }
    }
}

extern "C" void kernel_launch(void* const* d_in, const int* in_sizes, int n_in,
                              void* d_out, int out_size, void* d_ws, size_t ws_size,
                              hipStream_t stream) {
    const float* imgs  = (const float*)d_in[0];   // [16][64][64][64] f32
    const float* filts = (const float*)d_in[1];   // [1][64][64][3][3][2] f32
    float* out = (float*)d_out;                   // [16][64][64][64] f32
    (void)d_ws; (void)ws_size;                    // no workspace needed

    hipLaunchKernelGGL(conv_one, dim3(256), dim3(512), 0, stream, imgs, filts, out);
}